// Round 13
// baseline (271.233 us; speedup 1.0000x reference)
//
#include <hip/hip_runtime.h>
#include <hip/hip_cooperative_groups.h>
#include <stdint.h>

#define SEQ 256
#define BATCH 32
#define IN_DIM 1024
#define HID 64
#define ROWS (SEQ*BATCH)   // 8192
#define YW 448             // compact Y width: [K0|K1|K2|V0|V1|V2|Q] * 64

// workspace layout:
//  [0,16.78M)      Xbf (prep->gemm2), then DMh bf16 ΔM/Mstart [18.87 MB, spills into
//  [16.78M,19.40M) Wbf               dead Wbf region; ends 18,874,368 < bb @19,398,656]
//  [19.40M,..)     bb, gate (live throughout)
//  [19.53M,26.87M) Yc bf16 compact 8192x448 (gemm2 -> chunk/corr)
//  [26.87M,27.14M) lists (8x8192 u32) + cnts (8 u32)
#define XBF_OFF   0
#define DMH_OFF   0
#define WBF_OFF   16777216
#define BB_OFF    19398656
#define GATE_OFF  19403776
#define Y_OFF     19534848
#define LIST_OFF  26874880
#define CNT_OFF   27137024

#define NC 8
#define CHL 32      // chunk length; 96 triples per (b,c)

// DMh: per (c,b): bf16 [m(9)][i(64)][j(64)] = 36864 u16 = 73.7 KB; total 8*32 = 18.87 MB
#define DM_CB_U32 18432

typedef __attribute__((ext_vector_type(8))) short short8;
typedef __attribute__((ext_vector_type(4))) float floatx4;

typedef const __attribute__((address_space(1))) unsigned int gas_u32;
typedef __attribute__((address_space(3))) unsigned int las_u32;
static __device__ __forceinline__ void gl_lds16(const void* g, void* l) {
  __builtin_amdgcn_global_load_lds((gas_u32*)g, (las_u32*)l, 16, 0, 0);
}

static __device__ __forceinline__ short f2bf(float f) {
  union { float f; uint32_t u; } a; a.f = f;
  uint32_t r = (a.u + 0x7FFFu + ((a.u >> 16) & 1u)) >> 16;  // RNE
  return (short)r;
}
static __device__ __forceinline__ float bflo(uint32_t u){ return __uint_as_float(u << 16); }
static __device__ __forceinline__ float bfhi(uint32_t u){ return __uint_as_float(u & 0xffff0000u); }
static __device__ __forceinline__ float bfu(unsigned short us){ return __uint_as_float(((uint32_t)us) << 16); }

// ---------------- fused prep + gate ----------------
// Blocks [0,2048): row-wise — cast X->bf16 AND compute gate in ONE pass (X read once).
// Blocks [2048,2304): W cast + bias pack + zero routing counters.
__global__ __launch_bounds__(256) void prep_gate_kernel(
    const float* __restrict__ X,
    const float* __restrict__ Wk, const float* __restrict__ bk,
    const float* __restrict__ Wv, const float* __restrict__ bv,
    const float* __restrict__ Wg, const float* __restrict__ bg,
    const float* __restrict__ Wq, const float* __restrict__ bq,
    short* __restrict__ Xbf, short* __restrict__ Wbf,
    float* __restrict__ bb, float4* __restrict__ gate,
    uint32_t* __restrict__ cnts)
{
  if (blockIdx.x < 2048) {
    const int lane = threadIdx.x & 63;
    const int row  = blockIdx.x * 4 + (threadIdx.x >> 6);
    const float* x = X + (int64_t)row * IN_DIM;
    short4* xb = (short4*)(Xbf + (int64_t)row * IN_DIM);

    float acc[8];
#pragma unroll
    for (int e = 0; e < 8; e++) acc[e] = 0.f;
#pragma unroll
    for (int i = 0; i < 4; i++) {
      const int off = i * 256 + lane * 4;
      float4 xv = *(const float4*)(x + off);
      short4 s4;
      s4.x = f2bf(xv.x); s4.y = f2bf(xv.y); s4.z = f2bf(xv.z); s4.w = f2bf(xv.w);
      xb[i * 64 + lane] = s4;
#pragma unroll
      for (int e = 0; e < 8; e++) {
        float4 wv = *(const float4*)(Wg + e * IN_DIM + off);
        acc[e] += xv.x * wv.x + xv.y * wv.y + xv.z * wv.z + xv.w * wv.w;
      }
    }
#pragma unroll
    for (int e = 0; e < 8; e++) {
#pragma unroll
      for (int m = 32; m >= 1; m >>= 1)
        acc[e] += __shfl_xor(acc[e], m);
      acc[e] += bg[e];
    }
    if (lane == 0) {
      int i0 = 0; float v0 = acc[0];
#pragma unroll
      for (int e = 1; e < 8; e++) if (acc[e] > v0) { v0 = acc[e]; i0 = e; }
      int i1 = -1; float v1 = -3.4e38f;
#pragma unroll
      for (int e = 0; e < 8; e++) if (e != i0 && acc[e] > v1) { v1 = acc[e]; i1 = e; }
      float e1 = __expf(v1 - v0);
      float inv = 1.f / (1.f + e1);
      gate[row] = make_float4(__int_as_float(i0), __int_as_float(i1), inv, e1 * inv);
    }
  } else {
    const int idx = (blockIdx.x - 2048) * 256 + threadIdx.x;   // 65536 threads
    const int NW4 = 1216 * IN_DIM / 4;                         // 311296
#pragma unroll
    for (int i = idx; i < NW4; i += 65536) {
      int e = i * 4;
      int r = e >> 10;
      int k = e & 1023;
      float4 x;
      if (r < 576)       x = *(const float4*)(Wk + (int64_t)r*1024 + k);
      else if (r < 1152) x = *(const float4*)(Wv + (int64_t)(r-576)*1024 + k);
      else               x = *(const float4*)(Wq + (int64_t)(r-1152)*1024 + k);
      short4 s4;
      s4.x = f2bf(x.x); s4.y = f2bf(x.y); s4.z = f2bf(x.z); s4.w = f2bf(x.w);
      ((short4*)Wbf)[i] = s4;
    }
    if (idx < 1216) {
      int r = idx; float v;
      if (r < 576)       v = bk[r];
      else if (r < 1152) v = bv[r - 576];
      else               v = bq[r - 1152];
      bb[r] = v;
    }
    if (idx < 8) cnts[idx] = 0u;
  }
}

// ---------------- routing list build (LDS-aggregated; 256 global atomics total) ----------------
__global__ __launch_bounds__(256) void listbuild_kernel(
    const float4* __restrict__ gate, uint32_t* __restrict__ lists, uint32_t* __restrict__ cnts)
{
  __shared__ uint32_t lc[8];      // per-block counts
  __shared__ uint32_t lbase[8];   // per-block base in global list
  const int tid = threadIdx.x;
  const int row = blockIdx.x * 256 + tid;   // 8192
  if (tid < 8) lc[tid] = 0u;
  __syncthreads();
  float4 g = gate[row];
  const int i0 = __float_as_int(g.x), i1 = __float_as_int(g.y);
  uint32_t p0 = atomicAdd(&lc[i0], 1u);
  uint32_t p1 = atomicAdd(&lc[i1], 1u);
  __syncthreads();
  if (tid < 8) lbase[tid] = atomicAdd(&cnts[tid], lc[tid]);
  __syncthreads();
  lists[i0 * 8192 + lbase[i0] + p0] = (uint32_t)row;              // j=0 -> slot 1
  lists[i1 * 8192 + lbase[i1] + p1] = (uint32_t)row | (1u << 13); // j=1 -> slot 2
}

// ---------------- GEMM2: dense (K0,V0,Q) + routed (32-row blocks), BK=64 ----------------
// Compact Y layout per row: [K0 K1 K2 V0 V1 V2 Q] x 64 = 448 bf16.
// blocks [0,128): dense, 64 rows x 192 cols.
// blocks [128,2176): routed, head h = (blk-128)>>8, 32 gathered rows x 128 cols,
// early-exit past count (~512 active) -> ~640 active blocks total = 2.5/CU.
// Wbf rows: Wk 0..575 (9 heads x 64), Wv 576..1151, Wq 1152..1215.
// Routed head h: K rows 64*h..+63, V rows 576+64*h..+63.
// ALL gl_lds16 LDS destinations are WAVE-UNIFORM (m104/m108); per-lane GLOBAL
// addresses order lanes: lane l -> row +(l>>2), col-chunk (l&3)*8 per 16-row span.
__global__ __launch_bounds__(256) void gemm2_kernel(
    const short* __restrict__ Xbf, const short* __restrict__ Wbf,
    const float* __restrict__ bb, const uint32_t* __restrict__ lists,
    const uint32_t* __restrict__ cnts, unsigned short* __restrict__ Yc)
{
  __shared__ short As[128 * 32];     // 8KB  (dense: 2 panels 64x32; routed: 2 panels 32x32)
  __shared__ short Bs[384 * 32];     // 24KB (dense: 2 panels 192x32; routed: 2 panels 128x32)
  __shared__ uint32_t rl[32];

  const int tid  = threadIdx.x;
  const int lane = tid & 63;
  const int wv   = tid >> 6;
  const int quad = lane >> 4;
  const int cl   = lane & 15;
  const int wm   = wv & 1;
  const int wn   = wv >> 1;
  const int srow16 = lane >> 2;        // 0..15
  const int scol   = (lane & 3) * 8;   // shorts

  if (blockIdx.x < 128) {
    // ---------- dense: rows m0..m0+63, cols 192, BK=64 ----------
    const int m0 = blockIdx.x * 64;
    const short* gA = Xbf + (int64_t)(m0 + wv * 16 + srow16) * IN_DIM + scol;
    const short* gB[3];
#pragma unroll
    for (int i = 0; i < 3; i++) {
      const int b16 = (wv * 3 + i) * 16;
      const int sb = b16 < 64 ? b16 : (b16 < 128 ? 512 + b16 : 1024 + b16);
      gB[i] = Wbf + (int64_t)(sb + srow16) * IN_DIM + scol;
    }
    floatx4 acc[2][6];
#pragma unroll
    for (int i = 0; i < 2; i++)
#pragma unroll
      for (int k = 0; k < 6; k++) acc[i][k] = (floatx4){0.f, 0.f, 0.f, 0.f};

    for (int ks = 0; ks < IN_DIM; ks += 64) {
      gl_lds16(gA + ks,      As + (wv * 16) * 32);
      gl_lds16(gA + ks + 32, As + 64 * 32 + (wv * 16) * 32);
#pragma unroll
      for (int i = 0; i < 3; i++) {
        gl_lds16(gB[i] + ks,      Bs + ((wv * 3 + i) * 16) * 32);
        gl_lds16(gB[i] + ks + 32, Bs + 192 * 32 + ((wv * 3 + i) * 16) * 32);
      }
      __syncthreads();
#pragma unroll
      for (int kc = 0; kc < 2; kc++) {
        short8 af[2], bf[6];
#pragma unroll
        for (int mt = 0; mt < 2; mt++)
          af[mt] = *(const short8*)(&As[kc * 64 * 32 + (wm * 32 + mt * 16 + cl) * 32 + quad * 8]);
#pragma unroll
        for (int nt = 0; nt < 6; nt++)
          bf[nt] = *(const short8*)(&Bs[kc * 192 * 32 + (wn * 96 + nt * 16 + cl) * 32 + quad * 8]);
#pragma unroll
        for (int mt = 0; mt < 2; mt++)
#pragma unroll
          for (int nt = 0; nt < 6; nt++)
            acc[mt][nt] = __builtin_amdgcn_mfma_f32_16x16x32_bf16(af[mt], bf[nt], acc[mt][nt], 0, 0, 0);
      }
      __syncthreads();
    }
#pragma unroll
    for (int nt = 0; nt < 6; nt++) {
      const int bcol = wn * 96 + nt * 16 + cl;                 // 0..191
      const float bias = bb[bcol < 64 ? bcol : (bcol < 128 ? 512 + bcol : 1024 + bcol)];
      const int dest = (bcol & 63) + 192 * (bcol >> 6);        // K0 / V0 / Q
#pragma unroll
      for (int mt = 0; mt < 2; mt++) {
#pragma unroll
        for (int r = 0; r < 4; r++) {
          const int row = m0 + wm * 32 + mt * 16 + quad * 4 + r;
          Yc[(int64_t)row * YW + dest] = (unsigned short)f2bf(acc[mt][nt][r] + bias);
        }
      }
    }
  } else {
    // ---------- routed: head h, 32 gathered rows x 128 cols, BK=64 ----------
    const int hb = blockIdx.x - 128;
    const int h  = hb >> 8;                 // 256 blocks per head
    const int bo = (hb & 255) * 32;
    const uint32_t cnt = cnts[h];
    if ((uint32_t)bo >= cnt) return;

    if (tid < 32) {
      uint32_t e = ((uint32_t)(bo + tid) < cnt) ? lists[h * 8192 + bo + tid] : 0xFFFFFFFFu;
      rl[tid] = e;
    }
    __syncthreads();

    // A staging: 2 panels x 32 rows x 32 shorts = 4 wave-issues.
    const int pa  = wv >> 1;
    const int ra0 = (wv & 1) * 16;
    const uint32_t eA = rl[ra0 + srow16];
    const short* gA = Xbf + (int64_t)(eA == 0xFFFFFFFFu ? 0 : (eA & 8191)) * IN_DIM + pa * 32 + scol;
    short* lA = As + pa * 32 * 32 + ra0 * 32;          // wave-uniform

    // B staging: 2 panels x 128 rows x 32 shorts = 16 issues, 4 per wave.
    const short* gBp[4];
    short* lBp[4];
#pragma unroll
    for (int it = 0; it < 4; it++) {
      const int slot = wv * 4 + it;
      const int p  = slot >> 3;
      const int rb = slot & 7;
      const int brow = rb * 16 + srow16;
      const int bg = brow < 64 ? 64 * h + brow : 576 + 64 * h + (brow - 64);  // K / V of head h
      gBp[it] = Wbf + (int64_t)bg * IN_DIM + p * 32 + scol;
      lBp[it] = Bs + p * 128 * 32 + rb * 16 * 32;      // wave-uniform
    }

    floatx4 acc[2][2];
#pragma unroll
    for (int i = 0; i < 2; i++)
#pragma unroll
      for (int k = 0; k < 2; k++) acc[i][k] = (floatx4){0.f, 0.f, 0.f, 0.f};

    for (int ks = 0; ks < IN_DIM; ks += 64) {
      gl_lds16(gA + ks, lA);
#pragma unroll
      for (int it = 0; it < 4; it++)
        gl_lds16(gBp[it] + ks, lBp[it]);
      __syncthreads();
#pragma unroll
      for (int kc = 0; kc < 2; kc++) {
        short8 af[2], bf[2];
#pragma unroll
        for (int mt = 0; mt < 2; mt++)
          af[mt] = *(const short8*)(&As[kc * 32 * 32 + (mt * 16 + cl) * 32 + quad * 8]);
#pragma unroll
        for (int nt = 0; nt < 2; nt++)
          bf[nt] = *(const short8*)(&Bs[kc * 128 * 32 + (wv * 32 + nt * 16 + cl) * 32 + quad * 8]);
#pragma unroll
        for (int mt = 0; mt < 2; mt++)
#pragma unroll
          for (int nt = 0; nt < 2; nt++)
            acc[mt][nt] = __builtin_amdgcn_mfma_f32_16x16x32_bf16(af[mt], bf[nt], acc[mt][nt], 0, 0, 0);
      }
      __syncthreads();
    }
#pragma unroll
    for (int nt = 0; nt < 2; nt++) {
      const int bcol = wv * 32 + nt * 16 + cl;                  // 0..127 (K|V of head h)
      const float bias = bb[bcol < 64 ? 64 * h + bcol : 512 + 64 * h + bcol]; // V: 576+64h+(bcol-64)
#pragma unroll
      for (int mt = 0; mt < 2; mt++) {
#pragma unroll
        for (int r = 0; r < 4; r++) {
          const int rr = mt * 16 + quad * 4 + r;                // 0..31
          const uint32_t e = rl[rr];
          if (e != 0xFFFFFFFFu) {
            const int row = e & 8191;
            const int j = (e >> 13) & 1;
            const int dest = (bcol < 64) ? (64 + 64 * j + bcol)
                                         : (256 + 64 * j + (bcol - 64));
            Yc[(int64_t)row * YW + dest] = (unsigned short)f2bf(acc[mt][nt][r] + bias);
          }
        }
      }
    }
  }
}

// ======================= MFMA chunk kernel (256 blocks x 512 threads) =======================
// Per (b,c): 96 triples e=3s+u. Compact Y: K at col 64u, V at 192+64u, Q at 384.
// dM striping rotated by 4 (5-unit shares -> S-light waves): per-wave MFMA 19/20.
__global__ __launch_bounds__(512) void mfma_chunk_kernel(
    const unsigned short* __restrict__ Yb, const float4* __restrict__ gate,
    unsigned short* __restrict__ DMu, float* __restrict__ out)
{
  __shared__ uint32_t Qs[32 * 32];          // bf16 pairs [t][dpair]
  __shared__ uint32_t Ks[96 * 32];          // bf16 pairs [e][dpair]
  __shared__ unsigned short Kts[64 * 104];  // K^T [d][e], pad 96->104
  __shared__ unsigned short Vts[64 * 104];  // V^T [d][e]
  __shared__ unsigned short Ps[32 * 104];   // P   [t][e]
  __shared__ float4 gl[32];
  __shared__ uint32_t su[96];               // slot of triple e

  const int blk = blockIdx.x;
  const int c   = blk & 7;
  const int b   = blk >> 3;
  const int tid = threadIdx.x;
  const int lane = tid & 63;
  const int wv  = tid >> 6;                 // 0..7
  const int quad = lane >> 4;
  const int cl  = lane & 15;
  const int t0  = c * CHL;

  // ---- stage gates + slot ids ----
  if (tid < 32) {
    float4 g = gate[(t0 + tid) * BATCH + b];
    gl[tid] = g;
    su[3 * tid]     = 0u;
    su[3 * tid + 1] = (uint32_t)__float_as_int(g.x);
    su[3 * tid + 2] = (uint32_t)__float_as_int(g.y);
  }

  // ---- stage K (natural + transposed), V (transposed) — direct compact reads ----
  for (int idx = tid; idx < 1536; idx += 512) {      // e = idx>>4, d4 = idx&15
    const int e = idx >> 4, d4 = idx & 15;
    const int s = (e * 171) >> 9;                    // e/3 (exact for e<96)
    const int u = e - 3 * s;
    const unsigned short* Yr = Yb + ((int64_t)(t0 + s) * BATCH + b) * YW;
    uint2 kp = *(const uint2*)(Yr + 64 * u + 4 * d4);
    *(uint2*)&Ks[e * 32 + 2 * d4] = kp;
    Kts[(4 * d4)     * 104 + e] = (unsigned short)(kp.x & 0xffffu);
    Kts[(4 * d4 + 1) * 104 + e] = (unsigned short)(kp.x >> 16);
    Kts[(4 * d4 + 2) * 104 + e] = (unsigned short)(kp.y & 0xffffu);
    Kts[(4 * d4 + 3) * 104 + e] = (unsigned short)(kp.y >> 16);
    uint2 vp = *(const uint2*)(Yr + 192 + 64 * u + 4 * d4);
    Vts[(4 * d4)     * 104 + e] = (unsigned short)(vp.x & 0xffffu);
    Vts[(4 * d4 + 1) * 104 + e] = (unsigned short)(vp.x >> 16);
    Vts[(4 * d4 + 2) * 104 + e] = (unsigned short)(vp.y & 0xffffu);
    Vts[(4 * d4 + 3) * 104 + e] = (unsigned short)(vp.y >> 16);
  }
  {                                                   // Q: 512 entries, one per thread
    const int s = tid >> 4, d4 = tid & 15;
    const unsigned short* Yr = Yb + ((int64_t)(t0 + s) * BATCH + b) * YW;
    uint2 qp = *(const uint2*)(Yr + 384 + 4 * d4);
    *(uint2*)&Qs[s * 32 + 2 * d4] = qp;
  }
  __syncthreads();

  const unsigned short* Qu = (const unsigned short*)Qs;
  const unsigned short* Ku = (const unsigned short*)Ks;

  // ---- phase S + weight + pack P : 12 C-tiles over 8 waves ----
  for (int tileId = wv; tileId < 12; tileId += 8) {
    const int mt = tileId / 6, nt = tileId % 6;
    floatx4 acc = (floatx4){0.f, 0.f, 0.f, 0.f};
#pragma unroll
    for (int kc = 0; kc < 2; kc++) {
      short8 af = *(const short8*)(Qu + (mt * 16 + cl) * 64 + kc * 32 + quad * 8);
      short8 bf = *(const short8*)(Ku + (nt * 16 + cl) * 64 + kc * 32 + quad * 8);
      acc = __builtin_amdgcn_mfma_f32_16x16x32_bf16(af, bf, acc, 0, 0, 0);
    }
    const int e = nt * 16 + cl;
    const int s_e = (e * 171) >> 9;
    const int slot_e = (int)su[e];
#pragma unroll
    for (int r = 0; r < 4; r++) {
      const int t = mt * 16 + quad * 4 + r;
      float4 g = gl[t];
      const int i0t = __float_as_int(g.x), i1t = __float_as_int(g.y);
      float w = (slot_e == 0 ? 1.f : 0.f)
              + (slot_e == i0t ? g.z : 0.f)
              + (slot_e == i1t ? g.w : 0.f);
      w = (s_e <= t) ? w : 0.f;
      Ps[t * 104 + e] = (unsigned short)f2bf(w * acc[r]);
    }
  }
  __syncthreads();

  // ---- phase PV : o_local = P V, 8 C-tiles, one per wave ----
  {
    const int tileId = wv;                    // 0..7
    const int mt = tileId >> 2, nt = tileId & 3;
    floatx4 acc = (floatx4){0.f, 0.f, 0.f, 0.f};
#pragma unroll
    for (int kc = 0; kc < 3; kc++) {
      short8 af = *(const short8*)(Ps  + (mt * 16 + cl) * 104 + kc * 32 + quad * 8);
      short8 bf = *(const short8*)(Vts + (nt * 16 + cl) * 104 + kc * 32 + quad * 8);
      acc = __builtin_amdgcn_mfma_f32_16x16x32_bf16(af, bf, acc, 0, 0, 0);
    }
#pragma unroll
    for (int r = 0; r < 4; r++) {
      const int t = mt * 16 + quad * 4 + r, j = nt * 16 + cl;
      out[(int64_t)(t0 + t) * (BATCH * HID) + b * HID + j] = acc[r];
    }
  }

  // ---- phase dM : per slot m, D = K^T diag(slot==m) V ----
  uint32_t sreg[3][8];
#pragma unroll
  for (int kc = 0; kc < 3; kc++)
#pragma unroll
    for (int jj = 0; jj < 8; jj++)
      sreg[kc][jj] = su[kc * 32 + quad * 8 + jj];

  short8 afc[4][3];
#pragma unroll
  for (int mt = 0; mt < 4; mt++)
#pragma unroll
    for (int kc = 0; kc < 3; kc++)
      afc[mt][kc] = *(const short8*)(Kts + (mt * 16 + cl) * 104 + kc * 32 + quad * 8);

  unsigned short* dmb = DMu + ((int64_t)(c * 32 + b)) * 36864;
  union U8 { short8 s; uint32_t u[4]; };

  const int st = (wv + 4) & 7;                // rotate: 5-unit shares -> S-light waves 4-7
  for (int uu = st; uu < 36; uu += 8) {
    const int mi = uu >> 2, nt = uu & 3;
    uint32_t md[3][4];
#pragma unroll
    for (int kc = 0; kc < 3; kc++)
#pragma unroll
      for (int p = 0; p < 4; p++)
        md[kc][p] = ((sreg[kc][2 * p]     == (uint32_t)mi) ? 0x0000ffffu : 0u) |
                    ((sreg[kc][2 * p + 1] == (uint32_t)mi) ? 0xffff0000u : 0u);
    short8 bm[3];
#pragma unroll
    for (int kc = 0; kc < 3; kc++) {
      U8 vv; vv.s = *(const short8*)(Vts + (nt * 16 + cl) * 104 + kc * 32 + quad * 8);
      vv.u[0] &= md[kc][0]; vv.u[1] &= md[kc][1];
      vv.u[2] &= md[kc][2]; vv.u[3] &= md[kc][3];
      bm[kc] = vv.s;
    }
#pragma unroll
    for (int mt = 0; mt < 4; mt++) {
      floatx4 acc = (floatx4){0.f, 0.f, 0.f, 0.f};
#pragma unroll
      for (int kc = 0; kc < 3; kc++)
        acc = __builtin_amdgcn_mfma_f32_16x16x32_bf16(afc[mt][kc], bm[kc], acc, 0, 0, 0);
#pragma unroll
      for (int r = 0; r < 4; r++) {
        const int i = mt * 16 + quad * 4 + r, j = nt * 16 + cl;
        dmb[mi * 4096 + i * 64 + j] = (unsigned short)f2bf(acc[r]);
      }
    }
  }
}

// ============ fused prefix + corr (cooperative; removes one launch boundary) ============
// Phase A (prefix): grid-strided over 32*18432 units — identical per-element math/order.
// __threadfence (device scope, G16 cross-XCD visibility) + grid.sync().
// Phase B (corr): unchanged corr body, blk = blockIdx.x (grid is 512 x 256 = corr shape).
__global__ __launch_bounds__(256) void prefix_corr_kernel(
    const float* __restrict__ M0, uint32_t* __restrict__ DMh,
    const unsigned short* __restrict__ Yb, const float4* __restrict__ gate,
    float* __restrict__ out)
{
  __shared__ unsigned short MsbT[9 * 32 * 68];   // 39,168 B
  __shared__ float2 qb[32 * 32];                 // q fp32 pairs [t][i/2]
  __shared__ float4 gl[32];

  // ---- phase A: prefix ----
  const int64_t NTOT = (int64_t)32 * DM_CB_U32;          // 589,824
  for (int64_t e = (int64_t)blockIdx.x * 256 + threadIdx.x; e < NTOT; e += (int64_t)512 * 256) {
    int b = (int)(e / DM_CB_U32);
    int r = (int)(e % DM_CB_U32);             // m*2048 + i*32 + jpair
    int m = r >> 11, rem = r & 2047, i = rem >> 5, jp = rem & 31;
    int64_t f32i = (int64_t)b * 36864 + m * 4096 + i * 64 + jp * 2;
    float run0 = M0[f32i], run1 = M0[f32i + 1];
    uint32_t u[NC];
#pragma unroll
    for (int cc = 0; cc < NC; cc++)
      u[cc] = DMh[((int64_t)(cc * 32 + b)) * DM_CB_U32 + r];
#pragma unroll
    for (int cc = 0; cc < NC; cc++) {
      int64_t idx = ((int64_t)(cc * 32 + b)) * DM_CB_U32 + r;
      DMh[idx] = ((uint32_t)(unsigned short)f2bf(run0)) |
                 (((uint32_t)(unsigned short)f2bf(run1)) << 16);
      run0 += bflo(u[cc]); run1 += bfhi(u[cc]);
    }
    *(float2*)(out + (int64_t)SEQ * BATCH * HID + f32i) = make_float2(run0, run1);
  }

  __threadfence();                               // device-scope: cross-XCD visibility
  cooperative_groups::this_grid().sync();

  // ---- phase B: corr (unchanged) ----
  const int blk = blockIdx.x;
  const int c   = blk & 7;
  const int jh  = (blk >> 3) & 1;
  const int b   = blk >> 4;
  const int tid = threadIdx.x;
  const int t0  = c * CHL;

  if (tid < 32) gl[tid] = gate[(t0 + tid) * BATCH + b];
#pragma unroll
  for (int k = 0; k < 4; k++) {
    int f = tid + 256 * k;                // < 1024
    int t = f >> 5, p = f & 31;
    uint32_t u = *(const uint32_t*)(Yb + ((int64_t)(t0 + t) * BATCH + b) * YW + 384 + 2 * p);
    qb[t * 32 + p] = make_float2(bflo(u), bfhi(u));
  }
  const uint32_t* dmb = DMh + ((int64_t)(c * 32 + b)) * DM_CB_U32;
#pragma unroll
  for (int k = 0; k < 36; k++) {
    int f = tid + 256 * k;                // < 9216 u32
    int m = f >> 10, rem = f & 1023, i = rem >> 4, p = rem & 15;
    uint32_t u = dmb[m * 2048 + i * 32 + jh * 16 + p];
    MsbT[(m * 32 + 2 * p)     * 68 + i] = (unsigned short)(u & 0xffffu);
    MsbT[(m * 32 + 2 * p + 1) * 68 + i] = (unsigned short)(u >> 16);
  }
  __syncthreads();

  const int jj = tid & 31;
  const int tg = tid >> 5;
#pragma unroll
  for (int tt = 0; tt < 4; tt++) {
    const int t = tt * 8 + tg;
    float4 g = gl[t];
    const int i0 = __float_as_int(g.x), i1 = __float_as_int(g.y);
    const float g0 = g.z, g1 = g.w;
    const unsigned short* P0 = MsbT + (0  * 32 + jj) * 68;
    const unsigned short* Pa = MsbT + (i0 * 32 + jj) * 68;
    const unsigned short* Pb = MsbT + (i1 * 32 + jj) * 68;
    float acc = 0.f;
#pragma unroll 4
    for (int i4 = 0; i4 < 16; i4++) {     // 4 i's per step
      float2 qq0 = qb[t * 32 + 2 * i4];
      float2 qq1 = qb[t * 32 + 2 * i4 + 1];
      uint2 a0 = *(const uint2*)(P0 + 4 * i4);
      uint2 aa = *(const uint2*)(Pa + 4 * i4);
      uint2 ab = *(const uint2*)(Pb + 4 * i4);
      acc += qq0.x * (bflo(a0.x) + g0 * bflo(aa.x) + g1 * bflo(ab.x));
      acc += qq0.y * (bfhi(a0.x) + g0 * bfhi(aa.x) + g1 * bfhi(ab.x));
      acc += qq1.x * (bflo(a0.y) + g0 * bflo(aa.y) + g1 * bflo(ab.y));
      acc += qq1.y * (bfhi(a0.y) + g0 * bfhi(aa.y) + g1 * bfhi(ab.y));
    }
    float* op = out + (int64_t)(t0 + t) * (BATCH * HID) + b * HID + jh * 32 + jj;
    *op += acc;
  }
}

// ---------------- launch ----------------
extern "C" void kernel_launch(void* const* d_in, const int* in_sizes, int n_in,
                              void* d_out, int out_size, void* d_ws, size_t ws_size,
                              hipStream_t stream)
{
  const float* X  = (const float*)d_in[0];
  const float* M0 = (const float*)d_in[1];
  const float* Wk = (const float*)d_in[2];
  const float* bk = (const float*)d_in[3];
  const float* Wv = (const float*)d_in[4];
  const float* bv = (const float*)d_in[5];
  const float* Wg = (const float*)d_in[6];
  const float* bg = (const float*)d_in[7];
  const float* Wq = (const float*)d_in[8];
  const float* bq = (const float*)d_in[9];

  char* ws = (char*)d_ws;
  short*          Xbf   = (short*)(ws + XBF_OFF);
  short*          Wbf   = (short*)(ws + WBF_OFF);
  float*          bb    = (float*)(ws + BB_OFF);
  float4*         gate  = (float4*)(ws + GATE_OFF);
  unsigned short* Yc    = (unsigned short*)(ws + Y_OFF);
  uint32_t*       lists = (uint32_t*)(ws + LIST_OFF);
  uint32_t*       cnts  = (uint32_t*)(ws + CNT_OFF);
  uint32_t*       DMh   = (uint32_t*)(ws + DMH_OFF);       // overlays Xbf/Wbf (dead after gemm2)
  unsigned short* DMu   = (unsigned short*)(ws + DMH_OFF);
  float*          out   = (float*)d_out;

  prep_gate_kernel<<<2304, 256, 0, stream>>>(X, Wk, bk, Wv, bv, Wg, bg, Wq, bq,
                                             Xbf, Wbf, bb, gate, cnts);
  listbuild_kernel<<<32, 256, 0, stream>>>(gate, lists, cnts);
  gemm2_kernel<<<128 + 8 * 256, 256, 0, stream>>>(Xbf, Wbf, bb, lists, cnts, Yc);
  mfma_chunk_kernel<<<32 * NC, 512, 0, stream>>>(Yc, gate, DMu, out);

  void* args[] = { (void*)&M0, (void*)&DMh, (void*)&Yc, (void*)&gate, (void*)&out };
  hipLaunchCooperativeKernel((const void*)prefix_corr_kernel,
                             dim3(512), dim3(256), args, 0, stream);
}

// Round 14
// 159.976 us; speedup vs baseline: 1.6955x; 1.6955x over previous
//
#include <hip/hip_runtime.h>
#include <stdint.h>

#define SEQ 256
#define BATCH 32
#define IN_DIM 1024
#define HID 64
#define ROWS (SEQ*BATCH)   // 8192
#define YW 448             // compact Y width: [K0|K1|K2|V0|V1|V2|Q] * 64

// workspace layout:
//  [0,16.78M)      Xbf (prep->gemm2), then DMh bf16 ΔM/Mstart [18.87 MB, spills into
//  [16.78M,19.40M) Wbf               dead Wbf region; ends 18,874,368 < bb @19,398,656]
//  [19.40M,..)     bb, gate (live throughout)
//  [19.53M,26.87M) Yc bf16 compact 8192x448 (gemm2 -> chunk/corr)
//  [26.87M,27.14M) lists (8x8192 u32) + cnts (8 u32)
#define XBF_OFF   0
#define DMH_OFF   0
#define WBF_OFF   16777216
#define BB_OFF    19398656
#define GATE_OFF  19403776
#define Y_OFF     19534848
#define LIST_OFF  26874880
#define CNT_OFF   27137024

#define NC 8
#define CHL 32      // chunk length; 96 triples per (b,c)

// DMh: per (c,b): bf16 [m(9)][i(64)][j(64)] = 36864 u16 = 73.7 KB; total 8*32 = 18.87 MB
#define DM_CB_U32 18432

typedef __attribute__((ext_vector_type(8))) short short8;
typedef __attribute__((ext_vector_type(4))) float floatx4;

typedef const __attribute__((address_space(1))) unsigned int gas_u32;
typedef __attribute__((address_space(3))) unsigned int las_u32;
static __device__ __forceinline__ void gl_lds16(const void* g, void* l) {
  __builtin_amdgcn_global_load_lds((gas_u32*)g, (las_u32*)l, 16, 0, 0);
}

static __device__ __forceinline__ short f2bf(float f) {
  union { float f; uint32_t u; } a; a.f = f;
  uint32_t r = (a.u + 0x7FFFu + ((a.u >> 16) & 1u)) >> 16;  // RNE
  return (short)r;
}
static __device__ __forceinline__ float bflo(uint32_t u){ return __uint_as_float(u << 16); }
static __device__ __forceinline__ float bfhi(uint32_t u){ return __uint_as_float(u & 0xffff0000u); }
static __device__ __forceinline__ float bfu(unsigned short us){ return __uint_as_float(((uint32_t)us) << 16); }

// ---------------- fused prep + gate ----------------
// Blocks [0,2048): row-wise — cast X->bf16 AND compute gate in ONE pass (X read once).
// Blocks [2048,2304): W cast + bias pack + zero routing counters.
__global__ __launch_bounds__(256) void prep_gate_kernel(
    const float* __restrict__ X,
    const float* __restrict__ Wk, const float* __restrict__ bk,
    const float* __restrict__ Wv, const float* __restrict__ bv,
    const float* __restrict__ Wg, const float* __restrict__ bg,
    const float* __restrict__ Wq, const float* __restrict__ bq,
    short* __restrict__ Xbf, short* __restrict__ Wbf,
    float* __restrict__ bb, float4* __restrict__ gate,
    uint32_t* __restrict__ cnts)
{
  if (blockIdx.x < 2048) {
    const int lane = threadIdx.x & 63;
    const int row  = blockIdx.x * 4 + (threadIdx.x >> 6);
    const float* x = X + (int64_t)row * IN_DIM;
    short4* xb = (short4*)(Xbf + (int64_t)row * IN_DIM);

    float acc[8];
#pragma unroll
    for (int e = 0; e < 8; e++) acc[e] = 0.f;
#pragma unroll
    for (int i = 0; i < 4; i++) {
      const int off = i * 256 + lane * 4;
      float4 xv = *(const float4*)(x + off);
      short4 s4;
      s4.x = f2bf(xv.x); s4.y = f2bf(xv.y); s4.z = f2bf(xv.z); s4.w = f2bf(xv.w);
      xb[i * 64 + lane] = s4;
#pragma unroll
      for (int e = 0; e < 8; e++) {
        float4 wv = *(const float4*)(Wg + e * IN_DIM + off);
        acc[e] += xv.x * wv.x + xv.y * wv.y + xv.z * wv.z + xv.w * wv.w;
      }
    }
#pragma unroll
    for (int e = 0; e < 8; e++) {
#pragma unroll
      for (int m = 32; m >= 1; m >>= 1)
        acc[e] += __shfl_xor(acc[e], m);
      acc[e] += bg[e];
    }
    if (lane == 0) {
      int i0 = 0; float v0 = acc[0];
#pragma unroll
      for (int e = 1; e < 8; e++) if (acc[e] > v0) { v0 = acc[e]; i0 = e; }
      int i1 = -1; float v1 = -3.4e38f;
#pragma unroll
      for (int e = 0; e < 8; e++) if (e != i0 && acc[e] > v1) { v1 = acc[e]; i1 = e; }
      float e1 = __expf(v1 - v0);
      float inv = 1.f / (1.f + e1);
      gate[row] = make_float4(__int_as_float(i0), __int_as_float(i1), inv, e1 * inv);
    }
  } else {
    const int idx = (blockIdx.x - 2048) * 256 + threadIdx.x;   // 65536 threads
    const int NW4 = 1216 * IN_DIM / 4;                         // 311296
#pragma unroll
    for (int i = idx; i < NW4; i += 65536) {
      int e = i * 4;
      int r = e >> 10;
      int k = e & 1023;
      float4 x;
      if (r < 576)       x = *(const float4*)(Wk + (int64_t)r*1024 + k);
      else if (r < 1152) x = *(const float4*)(Wv + (int64_t)(r-576)*1024 + k);
      else               x = *(const float4*)(Wq + (int64_t)(r-1152)*1024 + k);
      short4 s4;
      s4.x = f2bf(x.x); s4.y = f2bf(x.y); s4.z = f2bf(x.z); s4.w = f2bf(x.w);
      ((short4*)Wbf)[i] = s4;
    }
    if (idx < 1216) {
      int r = idx; float v;
      if (r < 576)       v = bk[r];
      else if (r < 1152) v = bv[r - 576];
      else               v = bq[r - 1152];
      bb[r] = v;
    }
    if (idx < 8) cnts[idx] = 0u;
  }
}

// ---------------- routing list build (LDS-aggregated; 256 global atomics total) ----------------
__global__ __launch_bounds__(256) void listbuild_kernel(
    const float4* __restrict__ gate, uint32_t* __restrict__ lists, uint32_t* __restrict__ cnts)
{
  __shared__ uint32_t lc[8];      // per-block counts
  __shared__ uint32_t lbase[8];   // per-block base in global list
  const int tid = threadIdx.x;
  const int row = blockIdx.x * 256 + tid;   // 8192
  if (tid < 8) lc[tid] = 0u;
  __syncthreads();
  float4 g = gate[row];
  const int i0 = __float_as_int(g.x), i1 = __float_as_int(g.y);
  uint32_t p0 = atomicAdd(&lc[i0], 1u);
  uint32_t p1 = atomicAdd(&lc[i1], 1u);
  __syncthreads();
  if (tid < 8) lbase[tid] = atomicAdd(&cnts[tid], lc[tid]);
  __syncthreads();
  lists[i0 * 8192 + lbase[i0] + p0] = (uint32_t)row;              // j=0 -> slot 1
  lists[i1 * 8192 + lbase[i1] + p1] = (uint32_t)row | (1u << 13); // j=1 -> slot 2
}

// ---------------- GEMM2: dense (K0,V0,Q) + routed (32-row blocks), BK=64 ----------------
// Compact Y layout per row: [K0 K1 K2 V0 V1 V2 Q] x 64 = 448 bf16.
// blocks [0,128): dense, 64 rows x 192 cols.
// blocks [128,2176): routed, head h = (blk-128)>>8, 32 gathered rows x 128 cols,
// early-exit past count (~512 active) -> ~640 active blocks total = 2.5/CU.
// Wbf rows: Wk 0..575 (9 heads x 64), Wv 576..1151, Wq 1152..1215.
// Routed head h: K rows 64*h..+63, V rows 576+64*h..+63.
// ALL gl_lds16 LDS destinations are WAVE-UNIFORM (m104/m108); per-lane GLOBAL
// addresses order lanes: lane l -> row +(l>>2), col-chunk (l&3)*8 per 16-row span.
__global__ __launch_bounds__(256) void gemm2_kernel(
    const short* __restrict__ Xbf, const short* __restrict__ Wbf,
    const float* __restrict__ bb, const uint32_t* __restrict__ lists,
    const uint32_t* __restrict__ cnts, unsigned short* __restrict__ Yc)
{
  __shared__ short As[128 * 32];     // 8KB  (dense: 2 panels 64x32; routed: 2 panels 32x32)
  __shared__ short Bs[384 * 32];     // 24KB (dense: 2 panels 192x32; routed: 2 panels 128x32)
  __shared__ uint32_t rl[32];

  const int tid  = threadIdx.x;
  const int lane = tid & 63;
  const int wv   = tid >> 6;
  const int quad = lane >> 4;
  const int cl   = lane & 15;
  const int wm   = wv & 1;
  const int wn   = wv >> 1;
  const int srow16 = lane >> 2;        // 0..15
  const int scol   = (lane & 3) * 8;   // shorts

  if (blockIdx.x < 128) {
    // ---------- dense: rows m0..m0+63, cols 192, BK=64 ----------
    const int m0 = blockIdx.x * 64;
    const short* gA = Xbf + (int64_t)(m0 + wv * 16 + srow16) * IN_DIM + scol;
    const short* gB[3];
#pragma unroll
    for (int i = 0; i < 3; i++) {
      const int b16 = (wv * 3 + i) * 16;
      const int sb = b16 < 64 ? b16 : (b16 < 128 ? 512 + b16 : 1024 + b16);
      gB[i] = Wbf + (int64_t)(sb + srow16) * IN_DIM + scol;
    }
    floatx4 acc[2][6];
#pragma unroll
    for (int i = 0; i < 2; i++)
#pragma unroll
      for (int k = 0; k < 6; k++) acc[i][k] = (floatx4){0.f, 0.f, 0.f, 0.f};

    for (int ks = 0; ks < IN_DIM; ks += 64) {
      gl_lds16(gA + ks,      As + (wv * 16) * 32);
      gl_lds16(gA + ks + 32, As + 64 * 32 + (wv * 16) * 32);
#pragma unroll
      for (int i = 0; i < 3; i++) {
        gl_lds16(gB[i] + ks,      Bs + ((wv * 3 + i) * 16) * 32);
        gl_lds16(gB[i] + ks + 32, Bs + 192 * 32 + ((wv * 3 + i) * 16) * 32);
      }
      __syncthreads();
#pragma unroll
      for (int kc = 0; kc < 2; kc++) {
        short8 af[2], bf[6];
#pragma unroll
        for (int mt = 0; mt < 2; mt++)
          af[mt] = *(const short8*)(&As[kc * 64 * 32 + (wm * 32 + mt * 16 + cl) * 32 + quad * 8]);
#pragma unroll
        for (int nt = 0; nt < 6; nt++)
          bf[nt] = *(const short8*)(&Bs[kc * 192 * 32 + (wn * 96 + nt * 16 + cl) * 32 + quad * 8]);
#pragma unroll
        for (int mt = 0; mt < 2; mt++)
#pragma unroll
          for (int nt = 0; nt < 6; nt++)
            acc[mt][nt] = __builtin_amdgcn_mfma_f32_16x16x32_bf16(af[mt], bf[nt], acc[mt][nt], 0, 0, 0);
      }
      __syncthreads();
    }
#pragma unroll
    for (int nt = 0; nt < 6; nt++) {
      const int bcol = wn * 96 + nt * 16 + cl;                 // 0..191
      const float bias = bb[bcol < 64 ? bcol : (bcol < 128 ? 512 + bcol : 1024 + bcol)];
      const int dest = (bcol & 63) + 192 * (bcol >> 6);        // K0 / V0 / Q
#pragma unroll
      for (int mt = 0; mt < 2; mt++) {
#pragma unroll
        for (int r = 0; r < 4; r++) {
          const int row = m0 + wm * 32 + mt * 16 + quad * 4 + r;
          Yc[(int64_t)row * YW + dest] = (unsigned short)f2bf(acc[mt][nt][r] + bias);
        }
      }
    }
  } else {
    // ---------- routed: head h, 32 gathered rows x 128 cols, BK=64 ----------
    const int hb = blockIdx.x - 128;
    const int h  = hb >> 8;                 // 256 blocks per head
    const int bo = (hb & 255) * 32;
    const uint32_t cnt = cnts[h];
    if ((uint32_t)bo >= cnt) return;

    if (tid < 32) {
      uint32_t e = ((uint32_t)(bo + tid) < cnt) ? lists[h * 8192 + bo + tid] : 0xFFFFFFFFu;
      rl[tid] = e;
    }
    __syncthreads();

    // A staging: 2 panels x 32 rows x 32 shorts = 4 wave-issues.
    const int pa  = wv >> 1;
    const int ra0 = (wv & 1) * 16;
    const uint32_t eA = rl[ra0 + srow16];
    const short* gA = Xbf + (int64_t)(eA == 0xFFFFFFFFu ? 0 : (eA & 8191)) * IN_DIM + pa * 32 + scol;
    short* lA = As + pa * 32 * 32 + ra0 * 32;          // wave-uniform

    // B staging: 2 panels x 128 rows x 32 shorts = 16 issues, 4 per wave.
    const short* gBp[4];
    short* lBp[4];
#pragma unroll
    for (int it = 0; it < 4; it++) {
      const int slot = wv * 4 + it;
      const int p  = slot >> 3;
      const int rb = slot & 7;
      const int brow = rb * 16 + srow16;
      const int bg = brow < 64 ? 64 * h + brow : 576 + 64 * h + (brow - 64);  // K / V of head h
      gBp[it] = Wbf + (int64_t)bg * IN_DIM + p * 32 + scol;
      lBp[it] = Bs + p * 128 * 32 + rb * 16 * 32;      // wave-uniform
    }

    floatx4 acc[2][2];
#pragma unroll
    for (int i = 0; i < 2; i++)
#pragma unroll
      for (int k = 0; k < 2; k++) acc[i][k] = (floatx4){0.f, 0.f, 0.f, 0.f};

    for (int ks = 0; ks < IN_DIM; ks += 64) {
      gl_lds16(gA + ks, lA);
#pragma unroll
      for (int it = 0; it < 4; it++)
        gl_lds16(gBp[it] + ks, lBp[it]);
      __syncthreads();
#pragma unroll
      for (int kc = 0; kc < 2; kc++) {
        short8 af[2], bf[2];
#pragma unroll
        for (int mt = 0; mt < 2; mt++)
          af[mt] = *(const short8*)(&As[kc * 32 * 32 + (mt * 16 + cl) * 32 + quad * 8]);
#pragma unroll
        for (int nt = 0; nt < 2; nt++)
          bf[nt] = *(const short8*)(&Bs[kc * 128 * 32 + (wv * 32 + nt * 16 + cl) * 32 + quad * 8]);
#pragma unroll
        for (int mt = 0; mt < 2; mt++)
#pragma unroll
          for (int nt = 0; nt < 2; nt++)
            acc[mt][nt] = __builtin_amdgcn_mfma_f32_16x16x32_bf16(af[mt], bf[nt], acc[mt][nt], 0, 0, 0);
      }
      __syncthreads();
    }
#pragma unroll
    for (int nt = 0; nt < 2; nt++) {
      const int bcol = wv * 32 + nt * 16 + cl;                  // 0..127 (K|V of head h)
      const float bias = bb[bcol < 64 ? 64 * h + bcol : 512 + 64 * h + bcol]; // V: 576+64h+(bcol-64)
#pragma unroll
      for (int mt = 0; mt < 2; mt++) {
#pragma unroll
        for (int r = 0; r < 4; r++) {
          const int rr = mt * 16 + quad * 4 + r;                // 0..31
          const uint32_t e = rl[rr];
          if (e != 0xFFFFFFFFu) {
            const int row = e & 8191;
            const int j = (e >> 13) & 1;
            const int dest = (bcol < 64) ? (64 + 64 * j + bcol)
                                         : (256 + 64 * j + (bcol - 64));
            Yc[(int64_t)row * YW + dest] = (unsigned short)f2bf(acc[mt][nt][r] + bias);
          }
        }
      }
    }
  }
}

// ======================= MFMA chunk kernel (256 blocks x 512 threads; R10 proven) =======================
// Per (b,c): 96 triples e=3s+u. Compact Y: K at col 64u, V at 192+64u, Q at 384.
__global__ __launch_bounds__(512) void mfma_chunk_kernel(
    const unsigned short* __restrict__ Yb, const float4* __restrict__ gate,
    unsigned short* __restrict__ DMu, float* __restrict__ out)
{
  __shared__ uint32_t Qs[32 * 32];          // bf16 pairs [t][dpair]
  __shared__ uint32_t Ks[96 * 32];          // bf16 pairs [e][dpair]
  __shared__ unsigned short Kts[64 * 104];  // K^T [d][e], pad 96->104
  __shared__ unsigned short Vts[64 * 104];  // V^T [d][e]
  __shared__ unsigned short Ps[32 * 104];   // P   [t][e]
  __shared__ float4 gl[32];
  __shared__ uint32_t su[96];               // slot of triple e

  const int blk = blockIdx.x;
  const int c   = blk & 7;
  const int b   = blk >> 3;
  const int tid = threadIdx.x;
  const int lane = tid & 63;
  const int wv  = tid >> 6;                 // 0..7
  const int quad = lane >> 4;
  const int cl  = lane & 15;
  const int t0  = c * CHL;

  // ---- stage gates + slot ids ----
  if (tid < 32) {
    float4 g = gate[(t0 + tid) * BATCH + b];
    gl[tid] = g;
    su[3 * tid]     = 0u;
    su[3 * tid + 1] = (uint32_t)__float_as_int(g.x);
    su[3 * tid + 2] = (uint32_t)__float_as_int(g.y);
  }

  // ---- stage K (natural + transposed), V (transposed) — direct compact reads ----
  for (int idx = tid; idx < 1536; idx += 512) {      // e = idx>>4, d4 = idx&15
    const int e = idx >> 4, d4 = idx & 15;
    const int s = (e * 171) >> 9;                    // e/3 (exact for e<96)
    const int u = e - 3 * s;
    const unsigned short* Yr = Yb + ((int64_t)(t0 + s) * BATCH + b) * YW;
    uint2 kp = *(const uint2*)(Yr + 64 * u + 4 * d4);
    *(uint2*)&Ks[e * 32 + 2 * d4] = kp;
    Kts[(4 * d4)     * 104 + e] = (unsigned short)(kp.x & 0xffffu);
    Kts[(4 * d4 + 1) * 104 + e] = (unsigned short)(kp.x >> 16);
    Kts[(4 * d4 + 2) * 104 + e] = (unsigned short)(kp.y & 0xffffu);
    Kts[(4 * d4 + 3) * 104 + e] = (unsigned short)(kp.y >> 16);
    uint2 vp = *(const uint2*)(Yr + 192 + 64 * u + 4 * d4);
    Vts[(4 * d4)     * 104 + e] = (unsigned short)(vp.x & 0xffffu);
    Vts[(4 * d4 + 1) * 104 + e] = (unsigned short)(vp.x >> 16);
    Vts[(4 * d4 + 2) * 104 + e] = (unsigned short)(vp.y & 0xffffu);
    Vts[(4 * d4 + 3) * 104 + e] = (unsigned short)(vp.y >> 16);
  }
  {                                                   // Q: 512 entries, one per thread
    const int s = tid >> 4, d4 = tid & 15;
    const unsigned short* Yr = Yb + ((int64_t)(t0 + s) * BATCH + b) * YW;
    uint2 qp = *(const uint2*)(Yr + 384 + 4 * d4);
    *(uint2*)&Qs[s * 32 + 2 * d4] = qp;
  }
  __syncthreads();

  const unsigned short* Qu = (const unsigned short*)Qs;
  const unsigned short* Ku = (const unsigned short*)Ks;

  // ---- phase S + weight + pack P : 12 C-tiles over 8 waves ----
  for (int tileId = wv; tileId < 12; tileId += 8) {
    const int mt = tileId / 6, nt = tileId % 6;
    floatx4 acc = (floatx4){0.f, 0.f, 0.f, 0.f};
#pragma unroll
    for (int kc = 0; kc < 2; kc++) {
      short8 af = *(const short8*)(Qu + (mt * 16 + cl) * 64 + kc * 32 + quad * 8);
      short8 bf = *(const short8*)(Ku + (nt * 16 + cl) * 64 + kc * 32 + quad * 8);
      acc = __builtin_amdgcn_mfma_f32_16x16x32_bf16(af, bf, acc, 0, 0, 0);
    }
    const int e = nt * 16 + cl;
    const int s_e = (e * 171) >> 9;
    const int slot_e = (int)su[e];
#pragma unroll
    for (int r = 0; r < 4; r++) {
      const int t = mt * 16 + quad * 4 + r;
      float4 g = gl[t];
      const int i0t = __float_as_int(g.x), i1t = __float_as_int(g.y);
      float w = (slot_e == 0 ? 1.f : 0.f)
              + (slot_e == i0t ? g.z : 0.f)
              + (slot_e == i1t ? g.w : 0.f);
      w = (s_e <= t) ? w : 0.f;
      Ps[t * 104 + e] = (unsigned short)f2bf(w * acc[r]);
    }
  }
  __syncthreads();

  // ---- phase PV : o_local = P V, 8 C-tiles, one per wave ----
  {
    const int tileId = wv;                    // 0..7
    const int mt = tileId >> 2, nt = tileId & 3;
    floatx4 acc = (floatx4){0.f, 0.f, 0.f, 0.f};
#pragma unroll
    for (int kc = 0; kc < 3; kc++) {
      short8 af = *(const short8*)(Ps  + (mt * 16 + cl) * 104 + kc * 32 + quad * 8);
      short8 bf = *(const short8*)(Vts + (nt * 16 + cl) * 104 + kc * 32 + quad * 8);
      acc = __builtin_amdgcn_mfma_f32_16x16x32_bf16(af, bf, acc, 0, 0, 0);
    }
#pragma unroll
    for (int r = 0; r < 4; r++) {
      const int t = mt * 16 + quad * 4 + r, j = nt * 16 + cl;
      out[(int64_t)(t0 + t) * (BATCH * HID) + b * HID + j] = acc[r];
    }
  }

  // ---- phase dM : per slot m, D = K^T diag(slot==m) V ----
  uint32_t sreg[3][8];
#pragma unroll
  for (int kc = 0; kc < 3; kc++)
#pragma unroll
    for (int jj = 0; jj < 8; jj++)
      sreg[kc][jj] = su[kc * 32 + quad * 8 + jj];

  short8 afc[4][3];
#pragma unroll
  for (int mt = 0; mt < 4; mt++)
#pragma unroll
    for (int kc = 0; kc < 3; kc++)
      afc[mt][kc] = *(const short8*)(Kts + (mt * 16 + cl) * 104 + kc * 32 + quad * 8);

  unsigned short* dmb = DMu + ((int64_t)(c * 32 + b)) * 36864;
  union U8 { short8 s; uint32_t u[4]; };

  for (int uu = wv; uu < 36; uu += 8) {       // (mi,nt) units striped: {5,5,5,5,4,4,4,4}
    const int mi = uu >> 2, nt = uu & 3;
    uint32_t md[3][4];
#pragma unroll
    for (int kc = 0; kc < 3; kc++)
#pragma unroll
      for (int p = 0; p < 4; p++)
        md[kc][p] = ((sreg[kc][2 * p]     == (uint32_t)mi) ? 0x0000ffffu : 0u) |
                    ((sreg[kc][2 * p + 1] == (uint32_t)mi) ? 0xffff0000u : 0u);
    short8 bm[3];
#pragma unroll
    for (int kc = 0; kc < 3; kc++) {
      U8 vv; vv.s = *(const short8*)(Vts + (nt * 16 + cl) * 104 + kc * 32 + quad * 8);
      vv.u[0] &= md[kc][0]; vv.u[1] &= md[kc][1];
      vv.u[2] &= md[kc][2]; vv.u[3] &= md[kc][3];
      bm[kc] = vv.s;
    }
#pragma unroll
    for (int mt = 0; mt < 4; mt++) {
      floatx4 acc = (floatx4){0.f, 0.f, 0.f, 0.f};
#pragma unroll
      for (int kc = 0; kc < 3; kc++)
        acc = __builtin_amdgcn_mfma_f32_16x16x32_bf16(afc[mt][kc], bm[kc], acc, 0, 0, 0);
#pragma unroll
      for (int r = 0; r < 4; r++) {
        const int i = mt * 16 + quad * 4 + r, j = nt * 16 + cl;
        dmb[mi * 4096 + i * 64 + j] = (unsigned short)f2bf(acc[r]);
      }
    }
  }
}

// ---------------- prefix: ΔM(bf16) -> Mstart(bf16) exclusive +M0; writes M_final fp32 ----------------
__global__ void prefix_kernel(const float* __restrict__ M0, uint32_t* __restrict__ DMh,
                              float* __restrict__ out)
{
  int64_t e = (int64_t)blockIdx.x * blockDim.x + threadIdx.x;   // < 32*18432 u32 units
  int b = (int)(e / DM_CB_U32);
  int r = (int)(e % DM_CB_U32);             // m*2048 + i*32 + jpair
  int m = r >> 11, rem = r & 2047, i = rem >> 5, jp = rem & 31;
  int64_t f32i = (int64_t)b * 36864 + m * 4096 + i * 64 + jp * 2;
  float run0 = M0[f32i], run1 = M0[f32i + 1];
  uint32_t u[NC];
#pragma unroll
  for (int cc = 0; cc < NC; cc++)
    u[cc] = DMh[((int64_t)(cc * 32 + b)) * DM_CB_U32 + r];
#pragma unroll
  for (int cc = 0; cc < NC; cc++) {
    int64_t idx = ((int64_t)(cc * 32 + b)) * DM_CB_U32 + r;
    DMh[idx] = ((uint32_t)(unsigned short)f2bf(run0)) |
               (((uint32_t)(unsigned short)f2bf(run1)) << 16);
    run0 += bflo(u[cc]); run1 += bfhi(u[cc]);
  }
  *(float2*)(out + (int64_t)SEQ * BATCH * HID + f32i) = make_float2(run0, run1);
}

// ---------------- corr: o += q·(Mstart[0] + g0·Mstart[i0] + g1·Mstart[i1]) ----------------
__global__ __launch_bounds__(256) void corr_kernel(
    const unsigned short* __restrict__ Yb, const float4* __restrict__ gate,
    const uint32_t* __restrict__ DMh, float* __restrict__ out)
{
  __shared__ unsigned short MsbT[9 * 32 * 68];   // 39,168 B
  __shared__ float2 qb[32 * 32];                 // q fp32 pairs [t][i/2]
  __shared__ float4 gl[32];
  const int blk = blockIdx.x;
  const int c   = blk & 7;
  const int jh  = (blk >> 3) & 1;
  const int b   = blk >> 4;
  const int tid = threadIdx.x;
  const int t0  = c * CHL;

  if (tid < 32) gl[tid] = gate[(t0 + tid) * BATCH + b];
#pragma unroll
  for (int k = 0; k < 4; k++) {
    int f = tid + 256 * k;                // < 1024
    int t = f >> 5, p = f & 31;
    uint32_t u = *(const uint32_t*)(Yb + ((int64_t)(t0 + t) * BATCH + b) * YW + 384 + 2 * p);
    qb[t * 32 + p] = make_float2(bflo(u), bfhi(u));
  }
  const uint32_t* dmb = DMh + ((int64_t)(c * 32 + b)) * DM_CB_U32;
#pragma unroll
  for (int k = 0; k < 36; k++) {
    int f = tid + 256 * k;                // < 9216 u32
    int m = f >> 10, rem = f & 1023, i = rem >> 4, p = rem & 15;
    uint32_t u = dmb[m * 2048 + i * 32 + jh * 16 + p];
    MsbT[(m * 32 + 2 * p)     * 68 + i] = (unsigned short)(u & 0xffffu);
    MsbT[(m * 32 + 2 * p + 1) * 68 + i] = (unsigned short)(u >> 16);
  }
  __syncthreads();

  const int jj = tid & 31;
  const int tg = tid >> 5;
#pragma unroll
  for (int tt = 0; tt < 4; tt++) {
    const int t = tt * 8 + tg;
    float4 g = gl[t];
    const int i0 = __float_as_int(g.x), i1 = __float_as_int(g.y);
    const float g0 = g.z, g1 = g.w;
    const unsigned short* P0 = MsbT + (0  * 32 + jj) * 68;
    const unsigned short* Pa = MsbT + (i0 * 32 + jj) * 68;
    const unsigned short* Pb = MsbT + (i1 * 32 + jj) * 68;
    float acc = 0.f;
#pragma unroll 4
    for (int i4 = 0; i4 < 16; i4++) {     // 4 i's per step
      float2 qq0 = qb[t * 32 + 2 * i4];
      float2 qq1 = qb[t * 32 + 2 * i4 + 1];
      uint2 a0 = *(const uint2*)(P0 + 4 * i4);
      uint2 aa = *(const uint2*)(Pa + 4 * i4);
      uint2 ab = *(const uint2*)(Pb + 4 * i4);
      acc += qq0.x * (bflo(a0.x) + g0 * bflo(aa.x) + g1 * bflo(ab.x));
      acc += qq0.y * (bfhi(a0.x) + g0 * bfhi(aa.x) + g1 * bfhi(ab.x));
      acc += qq1.x * (bflo(a0.y) + g0 * bflo(aa.y) + g1 * bflo(ab.y));
      acc += qq1.y * (bfhi(a0.y) + g0 * bfhi(aa.y) + g1 * bfhi(ab.y));
    }
    float* op = out + (int64_t)(t0 + t) * (BATCH * HID) + b * HID + jh * 32 + jj;
    *op += acc;
  }
}

// ---------------- launch ----------------
extern "C" void kernel_launch(void* const* d_in, const int* in_sizes, int n_in,
                              void* d_out, int out_size, void* d_ws, size_t ws_size,
                              hipStream_t stream)
{
  const float* X  = (const float*)d_in[0];
  const float* M0 = (const float*)d_in[1];
  const float* Wk = (const float*)d_in[2];
  const float* bk = (const float*)d_in[3];
  const float* Wv = (const float*)d_in[4];
  const float* bv = (const float*)d_in[5];
  const float* Wg = (const float*)d_in[6];
  const float* bg = (const float*)d_in[7];
  const float* Wq = (const float*)d_in[8];
  const float* bq = (const float*)d_in[9];

  char* ws = (char*)d_ws;
  short*          Xbf   = (short*)(ws + XBF_OFF);
  short*          Wbf   = (short*)(ws + WBF_OFF);
  float*          bb    = (float*)(ws + BB_OFF);
  float4*         gate  = (float4*)(ws + GATE_OFF);
  unsigned short* Yc    = (unsigned short*)(ws + Y_OFF);
  uint32_t*       lists = (uint32_t*)(ws + LIST_OFF);
  uint32_t*       cnts  = (uint32_t*)(ws + CNT_OFF);
  uint32_t*       DMh   = (uint32_t*)(ws + DMH_OFF);       // overlays Xbf/Wbf (dead after gemm2)
  unsigned short* DMu   = (unsigned short*)(ws + DMH_OFF);
  float*          out   = (float*)d_out;

  prep_gate_kernel<<<2304, 256, 0, stream>>>(X, Wk, bk, Wv, bv, Wg, bg, Wq, bq,
                                             Xbf, Wbf, bb, gate, cnts);
  listbuild_kernel<<<32, 256, 0, stream>>>(gate, lists, cnts);
  gemm2_kernel<<<128 + 8 * 256, 256, 0, stream>>>(Xbf, Wbf, bb, lists, cnts, Yc);
  mfma_chunk_kernel<<<32 * NC, 512, 0, stream>>>(Yc, gate, DMu, out);
  prefix_kernel<<<(32 * DM_CB_U32) / 256, 256, 0, stream>>>(M0, DMh, out);
  corr_kernel<<<32 * NC * 2, 256, 0, stream>>>(Yc, gate, DMh, out);
}